// Round 9
// baseline (526.772 us; speedup 1.0000x reference)
//
#include <hip/hip_runtime.h>

#define NN 100000
#define NE 1600000
#define D 128
#define NG 1024
#define SCAN_CHUNK 2048
#define NB ((NN + SCAN_CHUNK - 1) / SCAN_CHUNK)   // 49
#define GEMM_BLKS ((NN + 63) / 64)                // 1563
#define HIST_BLKS ((NE + 255) / 256)              // 6250
#define BOUNDS_BLKS 5                             // 5*256 >= NG+1

typedef float f4 __attribute__((ext_vector_type(4)));
typedef int   i2 __attribute__((ext_vector_type(2)));

// ---------------- GEMM body: out[r][c] = sum_k act(in[r][k]) * W[k][c] ----------------
// 64x128 tile, K in 8 double-buffered panels of 16. 256 thr, per-thread 4x8.
// Single barrier per panel: WRITE targets cur^1 whose readers passed the
// previous barrier; no wave can be reading cur^1 concurrently.
__device__ __forceinline__ void gemm_body(const float* __restrict__ in,
                                          const float* __restrict__ W,
                                          const float* __restrict__ bias_in,
                                          int relu_in,
                                          float* __restrict__ out,
                                          int blk) {
    __shared__ float xs[2][16][68];    // [buf][k][row] transposed panel (2-way max)
    __shared__ float ws[2][16][128];   // [buf][k][col] lane-sequential float4s

    int tid  = threadIdx.x;
    int row0 = blk * 64;

    int srow = tid >> 2;               // x staging row 0..63
    int skq  = (tid & 3) * 4;          // k-quad
    int wkr  = tid >> 5;               // W staging k-row
    int wcq  = (tid & 31) * 4;         // W col quad
    int tx = tid & 15, ty = tid >> 4;
    int r0 = ty * 4, c0 = tx * 4;      // cols c0 and c0+64

    float4 lx, lw0, lw1;

    auto LOAD = [&](int kp) {
        int k0 = kp * 16;
        int rg = row0 + srow; if (rg >= NN) rg = NN - 1;
        lx  = *(const float4*)(in + (size_t)rg * D + k0 + skq);
        lw0 = *(const float4*)(W + (size_t)(k0 + wkr) * D + wcq);
        lw1 = *(const float4*)(W + (size_t)(k0 + 8 + wkr) * D + wcq);
        if (relu_in) {
            float4 bb = *(const float4*)(bias_in + k0 + skq);
            lx.x = fmaxf(lx.x + bb.x, 0.f);
            lx.y = fmaxf(lx.y + bb.y, 0.f);
            lx.z = fmaxf(lx.z + bb.z, 0.f);
            lx.w = fmaxf(lx.w + bb.w, 0.f);
        }
    };
    auto WRITE = [&](int buf) {
        xs[buf][skq + 0][srow] = lx.x;
        xs[buf][skq + 1][srow] = lx.y;
        xs[buf][skq + 2][srow] = lx.z;
        xs[buf][skq + 3][srow] = lx.w;
        *(float4*)&ws[buf][wkr][wcq]     = lw0;
        *(float4*)&ws[buf][wkr + 8][wcq] = lw1;
    };

    float acc[4][8] = {};

    LOAD(0);
    WRITE(0);
    __syncthreads();

    for (int kp = 0; kp < 8; ++kp) {
        int cur = kp & 1;
        if (kp < 7) LOAD(kp + 1);      // global loads in flight over compute
#pragma unroll
        for (int kk = 0; kk < 16; ++kk) {
            float4 xa = *(const float4*)&xs[cur][kk][r0];
            float4 wa = *(const float4*)&ws[cur][kk][c0];
            float4 wb = *(const float4*)&ws[cur][kk][c0 + 64];
            float xv[4] = {xa.x, xa.y, xa.z, xa.w};
            float wv[8] = {wa.x, wa.y, wa.z, wa.w, wb.x, wb.y, wb.z, wb.w};
#pragma unroll
            for (int i = 0; i < 4; ++i)
#pragma unroll
                for (int j = 0; j < 8; ++j)
                    acc[i][j] += xv[i] * wv[j];
        }
        if (kp < 7) {
            WRITE(cur ^ 1);            // safe: cur^1 readers passed last barrier
            __syncthreads();
        }
    }

#pragma unroll
    for (int i = 0; i < 4; ++i) {
        int rg = row0 + r0 + i;
        if (rg < NN) {
            f4 o0 = {acc[i][0], acc[i][1], acc[i][2], acc[i][3]};
            f4 o1 = {acc[i][4], acc[i][5], acc[i][6], acc[i][7]};
            __builtin_nontemporal_store(o0, (f4*)(out + (size_t)rg * D + c0));
            __builtin_nontemporal_store(o1, (f4*)(out + (size_t)rg * D + c0 + 64));
        }
    }
}

// ---------------- K1: gemm1 (blocks 0..GEMM_BLKS) || hist (rest) ----------------
__global__ __launch_bounds__(256) void k_gemm1_hist(const float* __restrict__ x,
                                                    const float* __restrict__ W1,
                                                    float* __restrict__ bufA,
                                                    const int* __restrict__ dst,
                                                    int* __restrict__ deg) {
    int b = blockIdx.x;
    if (b < GEMM_BLKS) {
        gemm_body(x, W1, nullptr, 0, bufA, b);
    } else {
        int e = (b - GEMM_BLKS) * 256 + threadIdx.x;
        if (e < NE) atomicAdd(&deg[dst[e]], 1);
    }
}

// ---------------- layer-2 GEMM ----------------
__global__ __launch_bounds__(256) void k_gemm(const float* __restrict__ in,
                                              const float* __restrict__ W,
                                              const float* __restrict__ bias_in,
                                              float* __restrict__ out) {
    gemm_body(in, W, bias_in, 1, out, blockIdx.x);
}

// ---------------- K2: scanA (+dinv fused) || bounds ----------------
__global__ __launch_bounds__(256) void k_scanA(const int* __restrict__ deg,
                                               float* __restrict__ dinv,
                                               int* __restrict__ row_ptr,
                                               int* __restrict__ bsum,
                                               const int* __restrict__ batch,
                                               int* __restrict__ gstart) {
    int b = blockIdx.x, tid = threadIdx.x;
    if (b >= NB) {
        int g = (b - NB) * 256 + tid;
        if (g > NG) return;
        if (g == NG) { gstart[NG] = NN; return; }
        int lo = 0, hi = NN;               // first v with batch[v] >= g
        while (lo < hi) {
            int mid = (lo + hi) >> 1;
            if (batch[mid] < g) lo = mid + 1; else hi = mid;
        }
        gstart[g] = lo;
        return;
    }
    __shared__ int sh[256];
    int base = b * SCAN_CHUNK + tid * 8;
    int loc[8];
    int s = 0;
#pragma unroll
    for (int j = 0; j < 8; ++j) {
        int i = base + j;
        int d = (i < NN) ? deg[i] : 0;
        if (i < NN) dinv[i] = rsqrtf((float)(d + 1));   // +1 self-loop
        loc[j] = s;
        s += d;
    }
    sh[tid] = s;
    __syncthreads();
    for (int off = 1; off < 256; off <<= 1) {
        int v = (tid >= off) ? sh[tid - off] : 0;
        __syncthreads();
        sh[tid] += v;
        __syncthreads();
    }
    int excl = (tid == 0) ? 0 : sh[tid - 1];
#pragma unroll
    for (int j = 0; j < 8; ++j) {
        int i = base + j;
        if (i < NN) row_ptr[i] = excl + loc[j];
    }
    if (tid == 255) bsum[b] = sh[255];
}

// ---------------- K3: scanC with inline block-sum prefix ----------------
__global__ __launch_bounds__(256) void k_scanC(int* __restrict__ row_ptr,
                                               const int* __restrict__ bsum,
                                               int* __restrict__ fill) {
    __shared__ int sb[64];
    int tid = threadIdx.x;
    if (tid < NB) sb[tid] = bsum[tid];
    __syncthreads();
    int chunk = (blockIdx.x * 256) / SCAN_CHUNK;
    int pre = 0;
    for (int b = 0; b < chunk; ++b) pre += sb[b];   // uniform LDS broadcast
    int i = blockIdx.x * 256 + tid;
    if (i < NN) {
        int r = row_ptr[i] + pre;
        row_ptr[i] = r;
        fill[i] = r;
    }
    if (i == 0) row_ptr[NN] = NE;
}

// ---------------- CSR fill: csr[pos] = {src, norm} ----------------
__global__ __launch_bounds__(256) void k_fill(const int* __restrict__ src,
                                              const int* __restrict__ dst,
                                              const float* __restrict__ dinv,
                                              int* __restrict__ fill,
                                              int2* __restrict__ csr) {
    int e = blockIdx.x * 256 + threadIdx.x;
    if (e >= NE) return;
    int s = src[e], d = dst[e];
    float nrm = dinv[s] * dinv[d];
    int pos = atomicAdd(&fill[d], 1);
    csr[pos] = make_int2(s, __float_as_int(nrm));
}

// ---------------- gather: agg[v] = h[v]*dinv[v]^2 + sum_in h[s]*norm ----------------
__global__ __launch_bounds__(256) void k_gather(const float* __restrict__ h,
                                                const int* __restrict__ row_ptr,
                                                const int2* __restrict__ csr,
                                                const float* __restrict__ dinv,
                                                float* __restrict__ agg) {
    int t = blockIdx.x * 256 + threadIdx.x;   // NN*32 threads
    int v = t >> 5;
    if (v >= NN) return;
    int c = (t & 31) * 4;

    float di = dinv[v];
    float sl = di * di;
    float4 acc = *(const float4*)(h + (size_t)v * D + c);
    acc.x *= sl; acc.y *= sl; acc.z *= sl; acc.w *= sl;

    const i2* csr2 = (const i2*)csr;
    int p   = row_ptr[v];
    int end = row_ptr[v + 1];
    for (; p + 3 < end; p += 4) {
        i2 e0 = __builtin_nontemporal_load(csr2 + p);
        i2 e1 = __builtin_nontemporal_load(csr2 + p + 1);
        i2 e2 = __builtin_nontemporal_load(csr2 + p + 2);
        i2 e3 = __builtin_nontemporal_load(csr2 + p + 3);
        float n0 = __int_as_float(e0.y);
        float n1 = __int_as_float(e1.y);
        float n2 = __int_as_float(e2.y);
        float n3 = __int_as_float(e3.y);
        float4 h0 = *(const float4*)(h + (size_t)e0.x * D + c);
        float4 h1 = *(const float4*)(h + (size_t)e1.x * D + c);
        float4 h2 = *(const float4*)(h + (size_t)e2.x * D + c);
        float4 h3 = *(const float4*)(h + (size_t)e3.x * D + c);
        acc.x += h0.x * n0; acc.y += h0.y * n0; acc.z += h0.z * n0; acc.w += h0.w * n0;
        acc.x += h1.x * n1; acc.y += h1.y * n1; acc.z += h1.z * n1; acc.w += h1.w * n1;
        acc.x += h2.x * n2; acc.y += h2.y * n2; acc.z += h2.z * n2; acc.w += h2.w * n2;
        acc.x += h3.x * n3; acc.y += h3.y * n3; acc.z += h3.z * n3; acc.w += h3.w * n3;
    }
    for (; p < end; ++p) {
        i2 e0 = __builtin_nontemporal_load(csr2 + p);
        float n0 = __int_as_float(e0.y);
        float4 h0 = *(const float4*)(h + (size_t)e0.x * D + c);
        acc.x += h0.x * n0; acc.y += h0.y * n0; acc.z += h0.z * n0; acc.w += h0.w * n0;
    }
    f4 av = {acc.x, acc.y, acc.z, acc.w};
    __builtin_nontemporal_store(av, (f4*)(agg + (size_t)v * D + c));
}

// ---------------- fused pool + classifier (block per graph) ----------------
__global__ __launch_bounds__(128) void k_poolcls(const float* __restrict__ agg,
                                                 const float* __restrict__ b2,
                                                 const int* __restrict__ gstart,
                                                 const float* __restrict__ Wc,
                                                 const float* __restrict__ bc,
                                                 float* __restrict__ out) {
    int g = blockIdx.x;
    int c = threadIdx.x;
    int v0 = gstart[g], v1 = gstart[g + 1];
    float bb = b2[c];
    float acc = 0.f;
    int v = v0;
    for (; v + 7 < v1; v += 8) {            // 8-deep for latency
        float x0 = agg[(size_t)(v + 0) * D + c];
        float x1 = agg[(size_t)(v + 1) * D + c];
        float x2 = agg[(size_t)(v + 2) * D + c];
        float x3 = agg[(size_t)(v + 3) * D + c];
        float x4 = agg[(size_t)(v + 4) * D + c];
        float x5 = agg[(size_t)(v + 5) * D + c];
        float x6 = agg[(size_t)(v + 6) * D + c];
        float x7 = agg[(size_t)(v + 7) * D + c];
        acc += fmaxf(x0 + bb, 0.f) + fmaxf(x1 + bb, 0.f)
             + fmaxf(x2 + bb, 0.f) + fmaxf(x3 + bb, 0.f)
             + fmaxf(x4 + bb, 0.f) + fmaxf(x5 + bb, 0.f)
             + fmaxf(x6 + bb, 0.f) + fmaxf(x7 + bb, 0.f);
    }
    for (; v < v1; ++v)
        acc += fmaxf(agg[(size_t)v * D + c] + bb, 0.f);

    float inv = 1.0f / fmaxf((float)(v1 - v0), 1.0f);
    float pv = acc * inv;

    __shared__ float red[2][128];
    red[0][c] = pv * Wc[c * 2 + 0];
    red[1][c] = pv * Wc[c * 2 + 1];
    __syncthreads();
    if (c < 64) {
        float s = red[0][c] + red[0][c + 64];
        for (int off = 32; off; off >>= 1) s += __shfl_down(s, off);
        if (c == 0) out[g * 2 + 0] = s + bc[0];
    } else {
        int l = c - 64;
        float s = red[1][l] + red[1][l + 64];
        for (int off = 32; off; off >>= 1) s += __shfl_down(s, off);
        if (l == 0) out[g * 2 + 1] = s + bc[1];
    }
}

extern "C" void kernel_launch(void* const* d_in, const int* in_sizes, int n_in,
                              void* d_out, int out_size, void* d_ws, size_t ws_size,
                              hipStream_t stream) {
    const float* x     = (const float*)d_in[0];
    const int*   ei    = (const int*)d_in[1];
    const int*   batch = (const int*)d_in[2];
    const float* W1    = (const float*)d_in[3];
    const float* b1    = (const float*)d_in[4];
    const float* W2    = (const float*)d_in[5];
    const float* b2    = (const float*)d_in[6];
    const float* Wc    = (const float*)d_in[7];
    const float* bc    = (const float*)d_in[8];
    float* out = (float*)d_out;

    const int* src = ei;            // edge_index[0]
    const int* dst = ei + NE;       // edge_index[1]

    char* p = (char*)d_ws;
    int*   deg_i   = (int*)p;    p += 100352 * 4;
    float* dinv    = (float*)p;  p += 100352 * 4;
    int*   row_ptr = (int*)p;    p += 100352 * 4;   // NN+1 fits
    int*   fillc   = (int*)p;    p += 100352 * 4;
    int*   bsum    = (int*)p;    p += 256 * 4;
    int*   gstart  = (int*)p;    p += 1056 * 4;     // NG+1
    int2*  csr     = (int2*)p;   p += (size_t)NE * 8;
    float* bufA    = (float*)p;  p += (size_t)NN * D * 4;
    float* bufB    = (float*)p;  p += (size_t)NN * D * 4;

    hipMemsetAsync(deg_i, 0, 100352 * 4, stream);

    // K1: layer-1 GEMM || degree histogram
    k_gemm1_hist<<<GEMM_BLKS + HIST_BLKS, 256, 0, stream>>>(x, W1, bufA, dst, deg_i);
    // K2: scan phase A (+dinv) || graph bounds
    k_scanA<<<NB + BOUNDS_BLKS, 256, 0, stream>>>(deg_i, dinv, row_ptr, bsum, batch, gstart);
    // K3: scan finalize
    k_scanC<<<(NN + 255) / 256, 256, 0, stream>>>(row_ptr, bsum, fillc);
    // K4: CSR fill
    k_fill<<<HIST_BLKS, 256, 0, stream>>>(src, dst, dinv, fillc, csr);

    // layer 1 gather
    k_gather<<<NN * 32 / 256, 256, 0, stream>>>(bufA, row_ptr, csr, dinv, bufB);

    // layer 2 (bias1+relu fused into gemm load)
    k_gemm<<<GEMM_BLKS, 256, 0, stream>>>(bufB, W2, b1, bufA);
    k_gather<<<NN * 32 / 256, 256, 0, stream>>>(bufA, row_ptr, csr, dinv, bufB);

    // fused pooling (bias2+relu) + classifier
    k_poolcls<<<NG, 128, 0, stream>>>(bufB, b2, gstart, Wc, bc, out);
}

// Round 10
// 505.018 us; speedup vs baseline: 1.0431x; 1.0431x over previous
//
#include <hip/hip_runtime.h>

#define NN 100000
#define NE 1600000
#define D 128
#define NG 1024
#define SCAN_CHUNK 2048
#define NB ((NN + SCAN_CHUNK - 1) / SCAN_CHUNK)   // 49
#define GEMM_BLKS ((NN + 63) / 64)                // 1563
#define HIST_BLKS ((NE + 255) / 256)              // 6250
#define BOUNDS_BLKS 5                             // 5*256 >= NG+1

// ---------------- GEMM body: out[r][c] = sum_k act(in[r][k]) * W[k][c] ----------------
// 64x128 tile, K in 8 double-buffered panels of 16. 256 thr, per-thread 4x8.
// Single barrier per panel: WRITE targets cur^1, whose readers all passed the
// previous barrier.
__device__ __forceinline__ void gemm_body(const float* __restrict__ in,
                                          const float* __restrict__ W,
                                          const float* __restrict__ bias_in,
                                          int relu_in,
                                          float* __restrict__ out,
                                          int blk) {
    __shared__ float xs[2][16][68];    // [buf][k][row] transposed panel (2-way max)
    __shared__ float ws[2][16][128];   // [buf][k][col] lane-sequential float4s

    int tid  = threadIdx.x;
    int row0 = blk * 64;

    int srow = tid >> 2;               // x staging row 0..63
    int skq  = (tid & 3) * 4;          // k-quad
    int wkr  = tid >> 5;               // W staging k-row
    int wcq  = (tid & 31) * 4;         // W col quad
    int tx = tid & 15, ty = tid >> 4;
    int r0 = ty * 4, c0 = tx * 4;      // cols c0 and c0+64

    float4 lx, lw0, lw1;

    auto LOAD = [&](int kp) {
        int k0 = kp * 16;
        int rg = row0 + srow; if (rg >= NN) rg = NN - 1;
        lx  = *(const float4*)(in + (size_t)rg * D + k0 + skq);
        lw0 = *(const float4*)(W + (size_t)(k0 + wkr) * D + wcq);
        lw1 = *(const float4*)(W + (size_t)(k0 + 8 + wkr) * D + wcq);
        if (relu_in) {
            float4 bb = *(const float4*)(bias_in + k0 + skq);
            lx.x = fmaxf(lx.x + bb.x, 0.f);
            lx.y = fmaxf(lx.y + bb.y, 0.f);
            lx.z = fmaxf(lx.z + bb.z, 0.f);
            lx.w = fmaxf(lx.w + bb.w, 0.f);
        }
    };
    auto WRITE = [&](int buf) {
        xs[buf][skq + 0][srow] = lx.x;
        xs[buf][skq + 1][srow] = lx.y;
        xs[buf][skq + 2][srow] = lx.z;
        xs[buf][skq + 3][srow] = lx.w;
        *(float4*)&ws[buf][wkr][wcq]     = lw0;
        *(float4*)&ws[buf][wkr + 8][wcq] = lw1;
    };

    float acc[4][8] = {};

    LOAD(0);
    WRITE(0);
    __syncthreads();

    for (int kp = 0; kp < 8; ++kp) {
        int cur = kp & 1;
        if (kp < 7) LOAD(kp + 1);      // global loads in flight over compute
#pragma unroll
        for (int kk = 0; kk < 16; ++kk) {
            float4 xa = *(const float4*)&xs[cur][kk][r0];
            float4 wa = *(const float4*)&ws[cur][kk][c0];
            float4 wb = *(const float4*)&ws[cur][kk][c0 + 64];
            float xv[4] = {xa.x, xa.y, xa.z, xa.w};
            float wv[8] = {wa.x, wa.y, wa.z, wa.w, wb.x, wb.y, wb.z, wb.w};
#pragma unroll
            for (int i = 0; i < 4; ++i)
#pragma unroll
                for (int j = 0; j < 8; ++j)
                    acc[i][j] += xv[i] * wv[j];
        }
        if (kp < 7) {
            WRITE(cur ^ 1);            // safe: cur^1 readers passed last barrier
            __syncthreads();
        }
    }

#pragma unroll
    for (int i = 0; i < 4; ++i) {
        int rg = row0 + r0 + i;
        if (rg < NN) {
            *(float4*)(out + (size_t)rg * D + c0) =
                make_float4(acc[i][0], acc[i][1], acc[i][2], acc[i][3]);
            *(float4*)(out + (size_t)rg * D + c0 + 64) =
                make_float4(acc[i][4], acc[i][5], acc[i][6], acc[i][7]);
        }
    }
}

// ---------------- K1: gemm1 (blocks 0..GEMM_BLKS) || hist (rest) ----------------
__global__ __launch_bounds__(256) void k_gemm1_hist(const float* __restrict__ x,
                                                    const float* __restrict__ W1,
                                                    float* __restrict__ bufA,
                                                    const int* __restrict__ dst,
                                                    int* __restrict__ deg) {
    int b = blockIdx.x;
    if (b < GEMM_BLKS) {
        gemm_body(x, W1, nullptr, 0, bufA, b);
    } else {
        int e = (b - GEMM_BLKS) * 256 + threadIdx.x;
        if (e < NE) atomicAdd(&deg[dst[e]], 1);
    }
}

// ---------------- layer-2 GEMM ----------------
__global__ __launch_bounds__(256) void k_gemm(const float* __restrict__ in,
                                              const float* __restrict__ W,
                                              const float* __restrict__ bias_in,
                                              float* __restrict__ out) {
    gemm_body(in, W, bias_in, 1, out, blockIdx.x);
}

// ---------------- K2: scanA (+dinv fused) || bounds ----------------
__global__ __launch_bounds__(256) void k_scanA(const int* __restrict__ deg,
                                               float* __restrict__ dinv,
                                               int* __restrict__ row_ptr,
                                               int* __restrict__ bsum,
                                               const int* __restrict__ batch,
                                               int* __restrict__ gstart) {
    int b = blockIdx.x, tid = threadIdx.x;
    if (b >= NB) {
        int g = (b - NB) * 256 + tid;
        if (g > NG) return;
        if (g == NG) { gstart[NG] = NN; return; }
        int lo = 0, hi = NN;               // first v with batch[v] >= g
        while (lo < hi) {
            int mid = (lo + hi) >> 1;
            if (batch[mid] < g) lo = mid + 1; else hi = mid;
        }
        gstart[g] = lo;
        return;
    }
    __shared__ int sh[256];
    int base = b * SCAN_CHUNK + tid * 8;
    int loc[8];
    int s = 0;
#pragma unroll
    for (int j = 0; j < 8; ++j) {
        int i = base + j;
        int d = (i < NN) ? deg[i] : 0;
        if (i < NN) dinv[i] = rsqrtf((float)(d + 1));   // +1 self-loop
        loc[j] = s;
        s += d;
    }
    sh[tid] = s;
    __syncthreads();
    for (int off = 1; off < 256; off <<= 1) {
        int v = (tid >= off) ? sh[tid - off] : 0;
        __syncthreads();
        sh[tid] += v;
        __syncthreads();
    }
    int excl = (tid == 0) ? 0 : sh[tid - 1];
#pragma unroll
    for (int j = 0; j < 8; ++j) {
        int i = base + j;
        if (i < NN) row_ptr[i] = excl + loc[j];
    }
    if (tid == 255) bsum[b] = sh[255];
}

// ---------------- K3: scanC with inline block-sum prefix ----------------
__global__ __launch_bounds__(256) void k_scanC(int* __restrict__ row_ptr,
                                               const int* __restrict__ bsum,
                                               int* __restrict__ fill) {
    __shared__ int sb[64];
    int tid = threadIdx.x;
    if (tid < NB) sb[tid] = bsum[tid];
    __syncthreads();
    int chunk = (blockIdx.x * 256) / SCAN_CHUNK;
    int pre = 0;
    for (int b = 0; b < chunk; ++b) pre += sb[b];   // uniform LDS broadcast
    int i = blockIdx.x * 256 + tid;
    if (i < NN) {
        int r = row_ptr[i] + pre;
        row_ptr[i] = r;
        fill[i] = r;
    }
    if (i == 0) row_ptr[NN] = NE;
}

// ---------------- CSR fill: csr[pos] = {src, norm} ----------------
__global__ __launch_bounds__(256) void k_fill(const int* __restrict__ src,
                                              const int* __restrict__ dst,
                                              const float* __restrict__ dinv,
                                              int* __restrict__ fill,
                                              int2* __restrict__ csr) {
    int e = blockIdx.x * 256 + threadIdx.x;
    if (e >= NE) return;
    int s = src[e], d = dst[e];
    float nrm = dinv[s] * dinv[d];
    int pos = atomicAdd(&fill[d], 1);
    csr[pos] = make_int2(s, __float_as_int(nrm));
}

// ---------------- gather: agg[v] = h[v]*dinv[v]^2 + sum_in h[s]*norm ----------------
__global__ __launch_bounds__(256) void k_gather(const float* __restrict__ h,
                                                const int* __restrict__ row_ptr,
                                                const int2* __restrict__ csr,
                                                const float* __restrict__ dinv,
                                                float* __restrict__ agg) {
    int t = blockIdx.x * 256 + threadIdx.x;   // NN*32 threads
    int v = t >> 5;
    if (v >= NN) return;
    int c = (t & 31) * 4;

    float di = dinv[v];
    float sl = di * di;
    float4 acc = *(const float4*)(h + (size_t)v * D + c);
    acc.x *= sl; acc.y *= sl; acc.z *= sl; acc.w *= sl;

    int p   = row_ptr[v];
    int end = row_ptr[v + 1];
    for (; p + 3 < end; p += 4) {
        int2 e0 = csr[p], e1 = csr[p + 1], e2 = csr[p + 2], e3 = csr[p + 3];
        float n0 = __int_as_float(e0.y);
        float n1 = __int_as_float(e1.y);
        float n2 = __int_as_float(e2.y);
        float n3 = __int_as_float(e3.y);
        float4 h0 = *(const float4*)(h + (size_t)e0.x * D + c);
        float4 h1 = *(const float4*)(h + (size_t)e1.x * D + c);
        float4 h2 = *(const float4*)(h + (size_t)e2.x * D + c);
        float4 h3 = *(const float4*)(h + (size_t)e3.x * D + c);
        acc.x += h0.x * n0; acc.y += h0.y * n0; acc.z += h0.z * n0; acc.w += h0.w * n0;
        acc.x += h1.x * n1; acc.y += h1.y * n1; acc.z += h1.z * n1; acc.w += h1.w * n1;
        acc.x += h2.x * n2; acc.y += h2.y * n2; acc.z += h2.z * n2; acc.w += h2.w * n2;
        acc.x += h3.x * n3; acc.y += h3.y * n3; acc.z += h3.z * n3; acc.w += h3.w * n3;
    }
    for (; p < end; ++p) {
        int2 e0 = csr[p];
        float n0 = __int_as_float(e0.y);
        float4 h0 = *(const float4*)(h + (size_t)e0.x * D + c);
        acc.x += h0.x * n0; acc.y += h0.y * n0; acc.z += h0.z * n0; acc.w += h0.w * n0;
    }
    *(float4*)(agg + (size_t)v * D + c) = acc;
}

// ---------------- fused pool + classifier (block per graph) ----------------
__global__ __launch_bounds__(128) void k_poolcls(const float* __restrict__ agg,
                                                 const float* __restrict__ b2,
                                                 const int* __restrict__ gstart,
                                                 const float* __restrict__ Wc,
                                                 const float* __restrict__ bc,
                                                 float* __restrict__ out) {
    int g = blockIdx.x;
    int c = threadIdx.x;
    int v0 = gstart[g], v1 = gstart[g + 1];
    float bb = b2[c];
    float acc = 0.f;
    int v = v0;
    for (; v + 7 < v1; v += 8) {            // 8-deep for latency
        float x0 = agg[(size_t)(v + 0) * D + c];
        float x1 = agg[(size_t)(v + 1) * D + c];
        float x2 = agg[(size_t)(v + 2) * D + c];
        float x3 = agg[(size_t)(v + 3) * D + c];
        float x4 = agg[(size_t)(v + 4) * D + c];
        float x5 = agg[(size_t)(v + 5) * D + c];
        float x6 = agg[(size_t)(v + 6) * D + c];
        float x7 = agg[(size_t)(v + 7) * D + c];
        acc += fmaxf(x0 + bb, 0.f) + fmaxf(x1 + bb, 0.f)
             + fmaxf(x2 + bb, 0.f) + fmaxf(x3 + bb, 0.f)
             + fmaxf(x4 + bb, 0.f) + fmaxf(x5 + bb, 0.f)
             + fmaxf(x6 + bb, 0.f) + fmaxf(x7 + bb, 0.f);
    }
    for (; v < v1; ++v)
        acc += fmaxf(agg[(size_t)v * D + c] + bb, 0.f);

    float inv = 1.0f / fmaxf((float)(v1 - v0), 1.0f);
    float pv = acc * inv;

    __shared__ float red[2][128];
    red[0][c] = pv * Wc[c * 2 + 0];
    red[1][c] = pv * Wc[c * 2 + 1];
    __syncthreads();
    if (c < 64) {
        float s = red[0][c] + red[0][c + 64];
        for (int off = 32; off; off >>= 1) s += __shfl_down(s, off);
        if (c == 0) out[g * 2 + 0] = s + bc[0];
    } else {
        int l = c - 64;
        float s = red[1][l] + red[1][l + 64];
        for (int off = 32; off; off >>= 1) s += __shfl_down(s, off);
        if (l == 0) out[g * 2 + 1] = s + bc[1];
    }
}

extern "C" void kernel_launch(void* const* d_in, const int* in_sizes, int n_in,
                              void* d_out, int out_size, void* d_ws, size_t ws_size,
                              hipStream_t stream) {
    const float* x     = (const float*)d_in[0];
    const int*   ei    = (const int*)d_in[1];
    const int*   batch = (const int*)d_in[2];
    const float* W1    = (const float*)d_in[3];
    const float* b1    = (const float*)d_in[4];
    const float* W2    = (const float*)d_in[5];
    const float* b2    = (const float*)d_in[6];
    const float* Wc    = (const float*)d_in[7];
    const float* bc    = (const float*)d_in[8];
    float* out = (float*)d_out;

    const int* src = ei;            // edge_index[0]
    const int* dst = ei + NE;       // edge_index[1]

    char* p = (char*)d_ws;
    int*   deg_i   = (int*)p;    p += 100352 * 4;
    float* dinv    = (float*)p;  p += 100352 * 4;
    int*   row_ptr = (int*)p;    p += 100352 * 4;   // NN+1 fits
    int*   fillc   = (int*)p;    p += 100352 * 4;
    int*   bsum    = (int*)p;    p += 256 * 4;
    int*   gstart  = (int*)p;    p += 1056 * 4;     // NG+1
    int2*  csr     = (int2*)p;   p += (size_t)NE * 8;
    float* bufA    = (float*)p;  p += (size_t)NN * D * 4;
    float* bufB    = (float*)p;  p += (size_t)NN * D * 4;

    hipMemsetAsync(deg_i, 0, 100352 * 4, stream);

    // K1: layer-1 GEMM || degree histogram
    k_gemm1_hist<<<GEMM_BLKS + HIST_BLKS, 256, 0, stream>>>(x, W1, bufA, dst, deg_i);
    // K2: scan phase A (+dinv) || graph bounds
    k_scanA<<<NB + BOUNDS_BLKS, 256, 0, stream>>>(deg_i, dinv, row_ptr, bsum, batch, gstart);
    // K3: scan finalize
    k_scanC<<<(NN + 255) / 256, 256, 0, stream>>>(row_ptr, bsum, fillc);
    // K4: CSR fill
    k_fill<<<HIST_BLKS, 256, 0, stream>>>(src, dst, dinv, fillc, csr);

    // layer 1 gather
    k_gather<<<NN * 32 / 256, 256, 0, stream>>>(bufA, row_ptr, csr, dinv, bufB);

    // layer 2 (bias1+relu fused into gemm load)
    k_gemm<<<GEMM_BLKS, 256, 0, stream>>>(bufB, W2, b1, bufA);
    k_gather<<<NN * 32 / 256, 256, 0, stream>>>(bufA, row_ptr, csr, dinv, bufB);

    // fused pooling (bias2+relu) + classifier
    k_poolcls<<<NG, 128, 0, stream>>>(bufB, b2, gstart, Wc, bc, out);
}